// Round 12
// baseline (1676.542 us; speedup 1.0000x reference)
//
#include <hip/hip_runtime.h>
#include <cstdint>
#include <cmath>

// LSTM: B=64, T=2048, H=128, gates=4H=512. f32 throughout.
//
// Round 12 = Round 11 with the workspace-layout bug fixed. R11's fused path
// never ran: flags inserted before xg pushed the ws requirement to
// 98304+256MB, but ws_size is in [65536+256MB, 98304+256MB) (proven by R10's
// full-T chunking). Fix: flags (16KB) overlays the first 64KB header, which
// the fused path doesn't use; xg stays at ws+65536 -> same requirement R10 met.
//   blocks 0..63    = rec chains (R10 body), 1 block/CU via 96KB LDS.
//   blocks 64..4159 = xproj tiles (32 rows) on the other ~192 CUs.
// Tile (b, window w=32 steps) publishes flags[w*64+b] with device-scope
// RELEASE store; rec ACQUIRE-spins one window ahead. Deadlock-free: producers
// never wait; 64 spinning consumers < 256 CUs.

#define HID 128
#define G4  512
#define BB  64
#define TT  2048

typedef float v2f __attribute__((ext_vector_type(2)));
typedef float v4f __attribute__((ext_vector_type(4)));

#define PIN2(v) asm volatile("" : "+v"(v))
#define FMA2(A, B, C) __builtin_elementwise_fma((A), (B), (C))
#define LOG2E  1.442695041f

template<int CTRL>
__device__ __forceinline__ float dpp_mov(float v) {
    return __int_as_float(__builtin_amdgcn_update_dpp(
        0, __float_as_int(v), CTRL, 0xF, 0xF, true));
}
// 8-lane butterfly sum (validated R5-R10).
#define BF8(p) { p += dpp_mov<0xB1>(p); p += dpp_mov<0x4E>(p); p += dpp_mov<0x141>(p); }

// ---- shared xproj per-thread math: gate row j over 16 rows from LDS ----
__device__ __forceinline__ void xproj_rows16(const v4f* __restrict__ xrows,
                                             const float* __restrict__ W_ih,
                                             float bias, int j, float* __restrict__ acc) {
    const v4f* wr4 = reinterpret_cast<const v4f*>(W_ih + (size_t)j * HID);
    v2f wv[32];
    #pragma unroll
    for (int k = 0; k < 16; ++k) { const v4f t = wr4[k]; wv[2*k] = t.xy; wv[2*k+1] = t.zw; }
    #pragma unroll
    for (int k = 0; k < 32; ++k) PIN2(wv[k]);
    #pragma unroll
    for (int r = 0; r < 16; ++r) {                 // pass 0: k=0..63
        const v4f* xp = xrows + r * 32;
        v2f a0 = {0.f,0.f}, a1 = {0.f,0.f};
        #pragma unroll
        for (int k = 0; k < 16; ++k) {
            const v4f v = xp[k];
            a0 = FMA2(wv[2*k], v.xy, a0); a1 = FMA2(wv[2*k+1], v.zw, a1);
        }
        const v2f s = a0 + a1;
        acc[r] = bias + s.x + s.y;
    }
    #pragma unroll
    for (int k = 0; k < 16; ++k) { const v4f t = wr4[16+k]; wv[2*k] = t.xy; wv[2*k+1] = t.zw; }
    #pragma unroll
    for (int k = 0; k < 32; ++k) PIN2(wv[k]);
    #pragma unroll
    for (int r = 0; r < 16; ++r) {                 // pass 1: k=64..127
        const v4f* xp = xrows + r * 32 + 16;
        v2f a0 = {0.f,0.f}, a1 = {0.f,0.f};
        #pragma unroll
        for (int k = 0; k < 16; ++k) {
            const v4f v = xp[k];
            a0 = FMA2(wv[2*k], v.xy, a0); a1 = FMA2(wv[2*k+1], v.zw, a1);
        }
        const v2f s = a0 + a1;
        acc[r] += s.x + s.y;
    }
}

// ================= FUSED kernel =================
__global__ __launch_bounds__(1024)
__attribute__((amdgpu_waves_per_eu(4, 4)))
void lstm_fused_kernel(const float* __restrict__ x, const float* __restrict__ h0,
                       const float* __restrict__ c0, const float* __restrict__ W_ih,
                       const float* __restrict__ W_hh, const float* __restrict__ b_ih,
                       const float* __restrict__ b_hh, float* __restrict__ out,
                       float* __restrict__ xg, int* __restrict__ flags) {
    __shared__ __align__(16) float lds_pool[24576];   // 96 KB -> 1 block/CU
    const int t = threadIdx.x;

    if (blockIdx.x >= BB) {
        // ---------- producer: one 32-row xproj tile ----------
        const int tile = blockIdx.x - BB;
        const int bb   = tile & 63;                // batch
        const int w    = tile >> 6;                // 32-step window
        const int tc0  = w * 32;
        v4f* xs4 = reinterpret_cast<v4f*>(lds_pool);          // 1024 v4f = 16 KB
        const float* xsrc = x + ((size_t)bb * TT + tc0) * HID;
        xs4[t] = reinterpret_cast<const v4f*>(xsrc)[t];       // stage 32 rows
        const int j  = t & 511;                    // gate row
        const int rg = t >> 9;                     // row-group 0/1
        const float bias = b_ih[j] + b_hh[j];
        __syncthreads();

        float acc[16];
        xproj_rows16(xs4 + rg * 16 * 32, W_ih, bias, j, acc);

        // gate-interleaved: pos = hid*4 + gate
        float* dst = xg + ((size_t)bb * TT + tc0 + rg * 16) * G4
                        + ((j & 127) << 2) + (j >> 7);
        #pragma unroll
        for (int r = 0; r < 16; ++r)
            dst[(size_t)r * G4] = acc[r];

        __syncthreads();                           // all waves' stores drained
        if (t == 0)
            __hip_atomic_store(&flags[tile], 1, __ATOMIC_RELEASE,
                               __HIP_MEMORY_SCOPE_AGENT);
        return;
    }

    // ---------- consumer: recurrence chain b (R10 body) ----------
    const int g   = t >> 3;                        // unit 0..127
    const int l   = t & 7;                         // k-chunk lane
    const int sel = l & 3;                         // gate this lane owns
    const int b   = blockIdx.x;
    float* hl = lds_pool;                          // h_lds[2][160] overlay

    const float* wl = W_hh + 16 * l;
    v2f W[4][8];
    #pragma unroll
    for (int q = 0; q < 4; ++q) {
        const v4f* wp = reinterpret_cast<const v4f*>(wl + (size_t)(q * 128 + g) * HID);
        #pragma unroll
        for (int k = 0; k < 4; ++k) { const v4f tw = wp[k]; W[q][2*k] = tw.xy; W[q][2*k+1] = tw.zw; }
    }
    #pragma unroll
    for (int q = 0; q < 4; ++q)
        #pragma unroll
        for (int k = 0; k < 8; ++k) PIN2(W[q][k]);

    const bool  la   = (l & 1) != 0;
    const bool  lb   = (l & 2) != 0;
    const float negK = (sel == 2) ? -2.f * LOG2E : -LOG2E;
    const float gA   = (sel == 2) ? 2.f : 1.f;
    const float gB   = (sel == 2) ? -1.f : 0.f;

    float c = c0[b * HID + g];
    if (t < HID) {
        const int pi = 20 * (t >> 4) + (t & 15);
        hl[pi] = h0[b * HID + t];
    }
    __syncthreads();

    v2f hcv[8];
    #pragma unroll
    for (int k = 0; k < 4; ++k) {
        const v4f hv = *reinterpret_cast<const v4f*>(&hl[20 * l + 4 * k]);
        hcv[2*k] = hv.xy; hcv[2*k+1] = hv.zw;
    }

    // wait for windows 0 and 1 of this b (covers steps 0..63 incl. prefetch)
    #define WAITTILE(idx) { if (t == 0) {                                        \
        while (__hip_atomic_load(&flags[idx], __ATOMIC_ACQUIRE,                  \
                                 __HIP_MEMORY_SCOPE_AGENT) == 0)                 \
            __builtin_amdgcn_s_sleep(8); }                                       \
        __syncthreads(); }
    WAITTILE(b)                                    // w=0
    WAITTILE(64 + b)                               // w=1

    const float* xq   = xg  + (size_t)b * TT * G4 + 4 * g + sel;
    float*       outp = out + (size_t)b * TT * HID + g;
    float xn = xq[0];

    for (int tc = 0; tc < TT; ++tc) {
        if ((tc & 31) == 0 && tc != 0) {           // uniform: window boundary
            const int w1 = (tc >> 5) + 1;          // stay one window ahead
            if (w1 < 64) WAITTILE(w1 * 64 + b)
        }
        float xnn = xn;
        if (tc + 1 < TT)
            xnn = xq[(size_t)(tc + 1) * G4];       // issue next-step load early

        v2f pp0 = {0.f,0.f}, pp1 = {0.f,0.f}, pp2 = {0.f,0.f}, pp3 = {0.f,0.f};
        #pragma unroll
        for (int k = 0; k < 8; ++k) {
            pp0 = FMA2(W[0][k], hcv[k], pp0);
            pp1 = FMA2(W[1][k], hcv[k], pp1);
            pp2 = FMA2(W[2][k], hcv[k], pp2);
            pp3 = FMA2(W[3][k], hcv[k], pp3);
        }
        float p0 = pp0.x + pp0.y, p1 = pp1.x + pp1.y;
        float p2 = pp2.x + pp2.y, p3 = pp3.x + pp3.y;
        BF8(p0) BF8(p1) BF8(p2) BF8(p3)

        const float t01 = la ? p1 : p0;
        const float t23 = la ? p3 : p2;
        const float xv  = (lb ? t23 : t01) + xn;

        const float e = __builtin_amdgcn_exp2f(xv * negK);
        float r = __builtin_amdgcn_rcpf(1.f + e);
        r = fmaf(r, gA, gB);

        const float vi = dpp_mov<0x00>(r);
        const float vf = dpp_mov<0x55>(r);
        const float vg = dpp_mov<0xAA>(r);
        const float vo = dpp_mov<0xFF>(r);
        c = fmaf(vf, c, vi * vg);
        const float e2 = __builtin_amdgcn_exp2f(c * (-2.f * LOG2E));
        const float th = fmaf(2.f, __builtin_amdgcn_rcpf(1.f + e2), -1.f);
        const float h  = vo * th;

        const int nb = (tc + 1) & 1;
        if (l == 0) {
            hl[nb * 160 + 20 * (g >> 4) + (g & 15)] = h;
            outp[(size_t)tc * HID] = h;
        }
        __syncthreads();                           // ONE barrier per step
        #pragma unroll
        for (int k = 0; k < 4; ++k) {
            const v4f hv = *reinterpret_cast<const v4f*>(&hl[nb * 160 + 20 * l + 4 * k]);
            hcv[2*k] = hv.xy; hcv[2*k+1] = hv.zw;
        }
        xn = xnn;
    }
    #undef WAITTILE
}

// ================= fallback: R10 chunked two-kernel path =================
__global__ __launch_bounds__(512)
__attribute__((amdgpu_waves_per_eu(4, 4)))
void xproj_kernel(const float* __restrict__ x, const float* __restrict__ W_ih,
                  const float* __restrict__ b_ih, const float* __restrict__ b_hh,
                  float* __restrict__ xg, int t0, int Tc) {
    __shared__ __align__(16) v4f xs4[16 * 32];
    const int j    = threadIdx.x;
    const int row0 = blockIdx.x * 16;
    const int b    = row0 / Tc;
    const int tc0  = row0 % Tc;
    const float* xsrc = x + ((size_t)b * TT + (size_t)t0 + tc0) * HID;
    xs4[j] = reinterpret_cast<const v4f*>(xsrc)[j];
    const float bias = b_ih[j] + b_hh[j];
    __syncthreads();
    float acc[16];
    xproj_rows16(xs4, W_ih, bias, j, acc);
    float* dst = xg + ((size_t)b * Tc + tc0) * G4 + ((j & 127) << 2) + (j >> 7);
    #pragma unroll
    for (int r = 0; r < 16; ++r)
        dst[(size_t)r * G4] = acc[r];
}

__global__ __launch_bounds__(1024)
__attribute__((amdgpu_waves_per_eu(4, 4)))
void lstm_rec_kernel(const float* __restrict__ xg, const float* __restrict__ h0,
                     const float* __restrict__ c0, const float* __restrict__ W_hh,
                     float* __restrict__ out, float* __restrict__ hstate,
                     float* __restrict__ cstate, int t0, int Tc) {
    __shared__ __align__(16) float h_lds[2][160];
    const int t   = threadIdx.x;
    const int g   = t >> 3;
    const int l   = t & 7;
    const int sel = l & 3;
    const int b   = blockIdx.x;
    const float* wl = W_hh + 16 * l;
    v2f W[4][8];
    #pragma unroll
    for (int q = 0; q < 4; ++q) {
        const v4f* wp = reinterpret_cast<const v4f*>(wl + (size_t)(q * 128 + g) * HID);
        #pragma unroll
        for (int k = 0; k < 4; ++k) { const v4f tw = wp[k]; W[q][2*k] = tw.xy; W[q][2*k+1] = tw.zw; }
    }
    #pragma unroll
    for (int q = 0; q < 4; ++q)
        #pragma unroll
        for (int k = 0; k < 8; ++k) PIN2(W[q][k]);
    const bool  la   = (l & 1) != 0;
    const bool  lb   = (l & 2) != 0;
    const float negK = (sel == 2) ? -2.f * LOG2E : -LOG2E;
    const float gA   = (sel == 2) ? 2.f : 1.f;
    const float gB   = (sel == 2) ? -1.f : 0.f;
    float c = (t0 == 0) ? c0[b * HID + g] : cstate[b * HID + g];
    if (t < HID) {
        const int pi = 20 * (t >> 4) + (t & 15);
        h_lds[0][pi] = (t0 == 0) ? h0[b * HID + t] : hstate[b * HID + t];
    }
    __syncthreads();
    v2f hcv[8];
    #pragma unroll
    for (int k = 0; k < 4; ++k) {
        const v4f hv = *reinterpret_cast<const v4f*>(&h_lds[0][20 * l + 4 * k]);
        hcv[2*k] = hv.xy; hcv[2*k+1] = hv.zw;
    }
    const float* xq   = xg  + (size_t)b * Tc * G4 + 4 * g + sel;
    float*       outp = out + ((size_t)b * TT + t0) * HID + g;
    float xn = xq[0];
    for (int tc = 0; tc < Tc; ++tc) {
        float xnn = xn;
        if (tc + 1 < Tc)
            xnn = xq[(size_t)(tc + 1) * G4];
        v2f pp0 = {0.f,0.f}, pp1 = {0.f,0.f}, pp2 = {0.f,0.f}, pp3 = {0.f,0.f};
        #pragma unroll
        for (int k = 0; k < 8; ++k) {
            pp0 = FMA2(W[0][k], hcv[k], pp0);
            pp1 = FMA2(W[1][k], hcv[k], pp1);
            pp2 = FMA2(W[2][k], hcv[k], pp2);
            pp3 = FMA2(W[3][k], hcv[k], pp3);
        }
        float p0 = pp0.x + pp0.y, p1 = pp1.x + pp1.y;
        float p2 = pp2.x + pp2.y, p3 = pp3.x + pp3.y;
        BF8(p0) BF8(p1) BF8(p2) BF8(p3)
        const float t01 = la ? p1 : p0;
        const float t23 = la ? p3 : p2;
        const float xv  = (lb ? t23 : t01) + xn;
        const float e = __builtin_amdgcn_exp2f(xv * negK);
        float r = __builtin_amdgcn_rcpf(1.f + e);
        r = fmaf(r, gA, gB);
        const float vi = dpp_mov<0x00>(r);
        const float vf = dpp_mov<0x55>(r);
        const float vg = dpp_mov<0xAA>(r);
        const float vo = dpp_mov<0xFF>(r);
        c = fmaf(vf, c, vi * vg);
        const float e2 = __builtin_amdgcn_exp2f(c * (-2.f * LOG2E));
        const float th = fmaf(2.f, __builtin_amdgcn_rcpf(1.f + e2), -1.f);
        const float h  = vo * th;
        const int nb = (tc + 1) & 1;
        if (l == 0) {
            h_lds[nb][20 * (g >> 4) + (g & 15)] = h;
            outp[(size_t)tc * HID] = h;
        }
        __syncthreads();
        #pragma unroll
        for (int k = 0; k < 4; ++k) {
            const v4f hv = *reinterpret_cast<const v4f*>(&h_lds[nb][20 * l + 4 * k]);
            hcv[2*k] = hv.xy; hcv[2*k+1] = hv.zw;
        }
        xn = xnn;
    }
    if (l == 0) cstate[b * HID + g] = c;
    if (t < HID) {
        const int pi = 20 * (t >> 4) + (t & 15);
        hstate[b * HID + t] = h_lds[Tc & 1][pi];
    }
}

extern "C" void kernel_launch(void* const* d_in, const int* in_sizes, int n_in,
                              void* d_out, int out_size, void* d_ws, size_t ws_size,
                              hipStream_t stream) {
    const float* x    = (const float*)d_in[0];
    const float* h0   = (const float*)d_in[1];
    const float* c0   = (const float*)d_in[2];
    const float* W_ih = (const float*)d_in[3];
    const float* W_hh = (const float*)d_in[4];
    const float* b_ih = (const float*)d_in[5];
    const float* b_hh = (const float*)d_in[6];
    float* out = (float*)d_out;

    char*  ws = (char*)d_ws;
    float* xg = (float*)(ws + 65536);              // both paths
    const size_t xg_full = (size_t)BB * TT * G4 * sizeof(float);  // 256 MB

    if (ws_size >= 65536 + xg_full) {
        // fused producer-consumer. flags (16 KB) overlays the header, which
        // the fused path doesn't use for state. Same ws requirement as R10.
        int* flags = (int*)ws;
        hipMemsetAsync(flags, 0, 16384, stream);
        lstm_fused_kernel<<<dim3(BB + 4096), dim3(1024), 0, stream>>>(
            x, h0, c0, W_ih, W_hh, b_ih, b_hh, out, xg, flags);
        return;
    }

    // fallback: chunked sequential (R10 layout: hstate/cstate in header)
    float* hstate = (float*)ws;
    float* cstate = (float*)(ws + 32768);
    const size_t per_t = (size_t)BB * G4 * sizeof(float);
    size_t avail = ws_size > 65536 ? ws_size - 65536 : 0;
    long long tc_ll = (long long)(avail / per_t);
    int Tc = tc_ll > TT ? TT : (int)tc_ll;
    Tc = (Tc / 64) * 64;
    if (Tc < 64) Tc = 64;
    for (int t0 = 0; t0 < TT; t0 += Tc) {
        const int Tcur = (TT - t0 < Tc) ? (TT - t0) : Tc;
        xproj_kernel<<<dim3(4 * Tcur), dim3(512), 0, stream>>>(x, W_ih, b_ih, b_hh,
                                                               xg, t0, Tcur);
        lstm_rec_kernel<<<dim3(BB), dim3(1024), 0, stream>>>(xg, h0, c0, W_hh, out,
                                                             hstate, cstate, t0, Tcur);
    }
}